// Round 1
// baseline (320.171 us; speedup 1.0000x reference)
//
#include <hip/hip_runtime.h>

// NarrativeClassificationLoss: one streaming pass over logits+labels,
// per-column partial sums (linear decomposition in pos_weight), tiny finalize.
//
// B=16384, N_NARR=128, N_SUB=1024, K=8, GAMMA=2, weights (1,1,0.5).

#define BDIM 256
#define NROWS 16384
#define NNARR 128
#define NSUB 1024
#define ROWS_PER_BLOCK 16
#define NBLOCKS (NROWS / ROWS_PER_BLOCK)   // 1024

// workspace float layout
#define WS_AN    0      // [128]  sum_b y*sp(-x)            (narrative)
#define WS_CN    128    // [128]  sum_b (1-y)*sp(x)
#define WS_NSUM  256    // [128]  column sums of narrative labels
#define WS_AS    384    // [1024] sum_b pos*y*sp(-x)        (subnarrative)
#define WS_CS    1408   // [1024] sum_b pos*(1-y)*sp(x)
#define WS_SSUM  2432   // [1024] column sums of sub labels (unmasked)
#define WS_FN    3456   // focal narrative sum
#define WS_FS    3457   // focal subnarrative sum
#define WS_HIER  3458   // hierarchy sum
#define WS_FLOATS 3459

__device__ __forceinline__ void bce_pieces(float x, float& sp_p, float& sp_m, float& sig) {
    // sp_p = softplus(x), sp_m = softplus(-x), sig = sigmoid(x)
    float a = fabsf(x);
    float e = __expf(-a);          // exp(-|x|) in (0,1]
    float l = log1pf(e);
    sp_p = fmaxf(x, 0.0f) + l;
    sp_m = sp_p - x;
    float inv = __builtin_amdgcn_rcpf(1.0f + e);
    sig = (x >= 0.0f) ? inv : e * inv;
}

__global__ __launch_bounds__(BDIM) void ncl_pass1(
    const float* __restrict__ nlog, const float* __restrict__ slog,
    const int*   __restrict__ nlab, const int*   __restrict__ slab,
    float* __restrict__ ws)
{
    __shared__ float nprob_s[2][NNARR];
    __shared__ float pos_s[2][NNARR];
    __shared__ float red[3][NNARR];

    const int t    = threadIdx.x;
    const int col  = t & 127;
    const int half = t >> 7;              // which of the 2 rows this thread's narr work hits
    const int g    = t >> 1;              // sub group index (cols 4t..4t+3 are in group t/2)
    const int row0 = blockIdx.x * ROWS_PER_BLOCK;

    float An = 0.f, Cn = 0.f, nsum = 0.f;
    float As[4] = {0.f,0.f,0.f,0.f}, Cs[4] = {0.f,0.f,0.f,0.f}, ssum[4] = {0.f,0.f,0.f,0.f};
    float fn = 0.f, fs = 0.f, hier = 0.f;

    for (int p = 0; p < ROWS_PER_BLOCK / 2; ++p) {
        const int r0 = row0 + 2 * p;

        // ---- narrative phase: 256 threads cover 2 rows x 128 cols, coalesced ----
        {
            int idx = r0 * NNARR + t;     // == (r0+half)*128 + col
            float x = nlog[idx];
            float y = (float)nlab[idx];
            float sp_p, sp_m, sig;
            bce_pieces(x, sp_p, sp_m, sig);
            An   += y * sp_m;
            Cn   += (1.0f - y) * sp_p;
            nsum += y;
            float om = 1.0f - sig;
            fn += om * om * y * (-sp_m);  // log_sigmoid(x) = -softplus(-x)
            nprob_s[half][col] = sig;
            pos_s[half][col]   = y;
        }
        __syncthreads();

        // ---- subnarrative phase: each thread owns 4 contiguous cols, both rows ----
        #pragma unroll
        for (int h = 0; h < 2; ++h) {
            const int r = r0 + h;
            const float4 xs = *(const float4*)(slog + r * NSUB + 4 * t);
            const int4   ys = *(const int4*)  (slab + r * NSUB + 4 * t);
            const float posv = pos_s[h][g];
            const float xv[4] = {xs.x, xs.y, xs.z, xs.w};
            const float yv[4] = {(float)ys.x, (float)ys.y, (float)ys.z, (float)ys.w};
            float mymax = 0.0f;
            #pragma unroll
            for (int j = 0; j < 4; ++j) {
                float sp_p, sp_m, sig;
                bce_pieces(xv[j], sp_p, sp_m, sig);
                float y = yv[j];
                As[j]   += posv * y * sp_m;
                Cs[j]   += posv * (1.0f - y) * sp_p;
                ssum[j] += y;
                float om = 1.0f - sig;
                fs += om * om * y * (-sp_m);
                mymax = fmaxf(mymax, sig);
            }
            // group max over 8 cols = pair of adjacent threads
            float gmax = fmaxf(mymax, __shfl_xor(mymax, 1, 64));
            if ((t & 1) == 0)
                hier += fmaxf(gmax - nprob_s[h][g], 0.0f) * posv;
        }
        __syncthreads();
    }

    // ---- narrative column partials: fold half==1 into half==0, then atomics ----
    if (half == 1) { red[0][col] = An; red[1][col] = Cn; red[2][col] = nsum; }
    __syncthreads();
    if (half == 0) {
        atomicAdd(&ws[WS_AN   + col], An   + red[0][col]);
        atomicAdd(&ws[WS_CN   + col], Cn   + red[1][col]);
        atomicAdd(&ws[WS_NSUM + col], nsum + red[2][col]);
    }

    // ---- sub column partials: each thread owns distinct cols ----
    #pragma unroll
    for (int j = 0; j < 4; ++j) {
        atomicAdd(&ws[WS_AS   + 4 * t + j], As[j]);
        atomicAdd(&ws[WS_CS   + 4 * t + j], Cs[j]);
        atomicAdd(&ws[WS_SSUM + 4 * t + j], ssum[j]);
    }

    // ---- scalar partials: wave shuffle reduce, one atomic per wave ----
    #pragma unroll
    for (int off = 32; off; off >>= 1) {
        fn   += __shfl_down(fn,   off, 64);
        fs   += __shfl_down(fs,   off, 64);
        hier += __shfl_down(hier, off, 64);
    }
    if ((t & 63) == 0) {
        atomicAdd(&ws[WS_FN],   fn);
        atomicAdd(&ws[WS_FS],   fs);
        atomicAdd(&ws[WS_HIER], hier);
    }
}

__global__ __launch_bounds__(1024) void ncl_finalize(const float* __restrict__ ws,
                                                     float* __restrict__ out)
{
    __shared__ float sr[3][16];
    const int t = threadIdx.x;
    const float Bf = (float)NROWS;

    // sub column t: combine with clamped pos_weight
    float s_sub = ws[WS_SSUM + t];
    float spw   = fminf(fmaxf((Bf - s_sub) / (s_sub + 1e-6f), 1.0f), 50.0f);
    float sub_part = spw * ws[WS_AS + t] + ws[WS_CS + t];

    float narr_part = 0.f, valid_part = 0.f;
    if (t < NNARR) {
        float s = ws[WS_NSUM + t];
        float npw = fminf(fmaxf((Bf - s) / (s + 1e-6f), 1.0f), 50.0f);
        narr_part  = npw * ws[WS_AN + t] + ws[WS_CN + t];
        valid_part = s;
    }

    #pragma unroll
    for (int off = 32; off; off >>= 1) {
        sub_part   += __shfl_down(sub_part,   off, 64);
        narr_part  += __shfl_down(narr_part,  off, 64);
        valid_part += __shfl_down(valid_part, off, 64);
    }
    if ((t & 63) == 0) {
        int w = t >> 6;
        sr[0][w] = sub_part; sr[1][w] = narr_part; sr[2][w] = valid_part;
    }
    __syncthreads();
    if (t == 0) {
        float sub_tot = 0.f, narr_tot = 0.f, valid = 0.f;
        #pragma unroll
        for (int i = 0; i < 16; ++i) { sub_tot += sr[0][i]; narr_tot += sr[1][i]; valid += sr[2][i]; }

        float narrative_loss = narr_tot / (Bf * (float)NNARR);
        float sub_loss = (valid > 0.0f) ? (sub_tot * (1.0f / 8.0f)) / fmaxf(valid, 1.0f) : 0.0f;
        float nf = ws[WS_FN] / (Bf * (float)NNARR);
        float sf = ws[WS_FS] / (Bf * (float)NSUB);
        float hier_loss = ws[WS_HIER] / Bf;

        out[0] = (narrative_loss - 0.1f * nf)
               + (sub_loss       - 0.1f * sf)
               + 0.5f * hier_loss;
    }
}

extern "C" void kernel_launch(void* const* d_in, const int* in_sizes, int n_in,
                              void* d_out, int out_size, void* d_ws, size_t ws_size,
                              hipStream_t stream) {
    const float* nlog = (const float*)d_in[0];
    const float* slog = (const float*)d_in[1];
    const int*   nlab = (const int*)d_in[2];
    const int*   slab = (const int*)d_in[3];
    float* ws  = (float*)d_ws;
    float* out = (float*)d_out;

    // workspace is re-poisoned to 0xAA before every call — zero the accumulators
    hipMemsetAsync(ws, 0, WS_FLOATS * sizeof(float), stream);

    ncl_pass1<<<NBLOCKS, BDIM, 0, stream>>>(nlog, slog, nlab, slab, ws);
    ncl_finalize<<<1, 1024, 0, stream>>>(ws, out);
}